// Round 1
// baseline (1793.549 us; speedup 1.0000x reference)
//
#include <hip/hip_runtime.h>

// GraphConv: out = LeakyReLU( (sum_k att_k A_k) @ (inputs@w + b), 0.2 )
// N=10000, C_in=C_out=128, N_ADJ=3, all fp32.

#define NN 10000
#define CC 128
#define NEG_SLOPE 0.2f

#define BN 32            // output rows per block (kernel 2)
#define BM 64            // m-chunk (K of big matmul) per staging step
#define SUP_ROWS 10048   // support rows padded to multiple of BM
#define NCHUNK 157       // ceil(10000/64)
#define SPLIT_CH 79      // z=0 does chunks [0,79), z=1 does [79,157)

// ---------------- kernel 1: support = inputs @ w + b ----------------
__global__ __launch_bounds__(256)
void support_kernel(const float* __restrict__ in, const float* __restrict__ w,
                    const float* __restrict__ b, float* __restrict__ sup) {
    __shared__ float s_in[16][CC];          // 8 KB
    const int tid = threadIdx.x;
    const int n0 = blockIdx.x * 16;         // 625 blocks * 16 rows = 10000 exact

    // stage 16 input rows (float4-coalesced)
    #pragma unroll
    for (int i = 0; i < 2; ++i) {
        int f4 = tid + i * 256;
        int r = f4 >> 5, c4 = (f4 & 31) * 4;
        *(float4*)&s_in[r][c4] = *(const float4*)&in[(n0 + r) * CC + c4];
    }
    __syncthreads();

    const int c = tid & 127, g = tid >> 7;  // thread: col c, rows g*8..g*8+7
    float acc[8];
    #pragma unroll
    for (int j = 0; j < 8; ++j) acc[j] = 0.f;

    for (int k = 0; k < CC; ++k) {
        float wk = w[k * CC + c];           // coalesced; w L2-resident (64 KB)
        #pragma unroll
        for (int j = 0; j < 8; ++j) acc[j] += s_in[g * 8 + j][k] * wk;
    }
    float bc = b[c];
    #pragma unroll
    for (int j = 0; j < 8; ++j)
        sup[(n0 + g * 8 + j) * CC + c] = acc[j] + bc;
}

// ------- kernel 2: partial[z] = (att-mixed adj chunk-range) @ support -------
__global__ __launch_bounds__(256)
void gc_main(const float* __restrict__ adj, const float* __restrict__ att_p,
             const float* __restrict__ sup, float* __restrict__ pbase) {
    __shared__ float s_sup[BM][CC];         // 32 KB
    __shared__ float s_mix[BN][BM + 1];     // 8.3 KB, +1 pad kills bank conflicts

    const int tid = threadIdx.x;
    const int n0 = blockIdx.x * BN;         // 313 blocks cover 10016 rows
    const int z  = blockIdx.y;
    const int ch_begin = z ? SPLIT_CH : 0;
    const int ch_end   = z ? NCHUNK   : SPLIT_CH;
    float* __restrict__ part = pbase + (size_t)z * NN * CC;

    const float att0 = att_p[0], att1 = att_p[1], att2 = att_p[2];
    const float* A0 = adj;
    const float* A1 = adj + (long long)NN * NN;
    const float* A2 = adj + 2LL * NN * NN;

    const int cg = tid & 31;                // 4 cols: cg*4 .. cg*4+3
    const int ng = tid >> 5;                // 4 rows: ng*4 .. ng*4+3
    float4 acc[4];
    #pragma unroll
    for (int i = 0; i < 4; ++i) acc[i] = make_float4(0.f, 0.f, 0.f, 0.f);

    for (int ch = ch_begin; ch < ch_end; ++ch) {
        const int m0 = ch * BM;
        __syncthreads();                    // previous compute done before restage

        // stage support chunk: rows m0..m0+63 (zero-padded past 10000)
        #pragma unroll
        for (int i = 0; i < 8; ++i) {
            int f4 = tid + i * 256;
            int r = f4 >> 5, c4 = (f4 & 31) * 4;
            *(float4*)&s_sup[r][c4] = *(const float4*)&sup[(m0 + r) * CC + c4];
        }
        // stage attention-mixed adjacency tile [BN x BM]
        #pragma unroll
        for (int i = 0; i < 2; ++i) {
            int f4 = tid + i * 256;
            int row = f4 >> 4, mc = (f4 & 15) * 4;
            int n = n0 + row, m = m0 + mc;
            float4 v = make_float4(0.f, 0.f, 0.f, 0.f);
            if (n < NN && m < NN) {
                long long off = (long long)n * NN + m;
                float4 a0 = *(const float4*)&A0[off];
                float4 a1 = *(const float4*)&A1[off];
                float4 a2 = *(const float4*)&A2[off];
                v.x = att0 * a0.x + att1 * a1.x + att2 * a2.x;
                v.y = att0 * a0.y + att1 * a1.y + att2 * a2.y;
                v.z = att0 * a0.z + att1 * a1.z + att2 * a2.z;
                v.w = att0 * a0.w + att1 * a1.w + att2 * a2.w;
            }
            *(float4*)&s_mix[row][mc] = v;
        }
        __syncthreads();

        // compute: 4n x 4c register tile; 16 FMA per m vs 1 b128 + 4 bcast b32
        #pragma unroll 8
        for (int m = 0; m < BM; ++m) {
            float4 sv = *(const float4*)&s_sup[m][cg * 4];
            float a0 = s_mix[ng * 4 + 0][m];
            float a1 = s_mix[ng * 4 + 1][m];
            float a2 = s_mix[ng * 4 + 2][m];
            float a3 = s_mix[ng * 4 + 3][m];
            acc[0].x += a0 * sv.x; acc[0].y += a0 * sv.y;
            acc[0].z += a0 * sv.z; acc[0].w += a0 * sv.w;
            acc[1].x += a1 * sv.x; acc[1].y += a1 * sv.y;
            acc[1].z += a1 * sv.z; acc[1].w += a1 * sv.w;
            acc[2].x += a2 * sv.x; acc[2].y += a2 * sv.y;
            acc[2].z += a2 * sv.z; acc[2].w += a2 * sv.w;
            acc[3].x += a3 * sv.x; acc[3].y += a3 * sv.y;
            acc[3].z += a3 * sv.z; acc[3].w += a3 * sv.w;
        }
    }

    #pragma unroll
    for (int i = 0; i < 4; ++i) {
        int n = n0 + ng * 4 + i;
        if (n < NN)
            *(float4*)&part[(size_t)n * CC + cg * 4] = acc[i];
    }
}

// ---------------- kernel 3: out = LeakyReLU(p0 + p1) ----------------
__global__ __launch_bounds__(256)
void combine_kernel(const float4* __restrict__ p0, const float4* __restrict__ p1,
                    float4* __restrict__ out) {
    int idx = blockIdx.x * 256 + threadIdx.x;   // 1250 blocks * 256 = 320000 exact
    float4 a = p0[idx];
    float4 b = p1[idx];
    float4 o;
    o.x = a.x + b.x; o.y = a.y + b.y; o.z = a.z + b.z; o.w = a.w + b.w;
    o.x = (o.x >= 0.f) ? o.x : NEG_SLOPE * o.x;
    o.y = (o.y >= 0.f) ? o.y : NEG_SLOPE * o.y;
    o.z = (o.z >= 0.f) ? o.z : NEG_SLOPE * o.z;
    o.w = (o.w >= 0.f) ? o.w : NEG_SLOPE * o.w;
    out[idx] = o;
}

extern "C" void kernel_launch(void* const* d_in, const int* in_sizes, int n_in,
                              void* d_out, int out_size, void* d_ws, size_t ws_size,
                              hipStream_t stream) {
    const float* inputs = (const float*)d_in[0];  // [10000,128]
    const float* adj    = (const float*)d_in[1];  // [3,10000,10000]
    const float* att    = (const float*)d_in[2];  // [3]
    const float* w      = (const float*)d_in[3];  // [128,128]
    const float* b      = (const float*)d_in[4];  // [128]
    float* out = (float*)d_out;                   // [10000,128]

    // ws layout: support[10048][128] | p0[10000][128] | p1[10000][128]  (~15.5 MB)
    float* sup = (float*)d_ws;
    float* p0  = sup + (size_t)SUP_ROWS * CC;

    // zero the padded support rows (ws is poisoned 0xAA before every launch)
    hipMemsetAsync(sup + (size_t)NN * CC, 0,
                   (size_t)(SUP_ROWS - NN) * CC * sizeof(float), stream);

    support_kernel<<<625, 256, 0, stream>>>(inputs, w, b, sup);
    gc_main<<<dim3(313, 2), 256, 0, stream>>>(adj, att, sup, p0);
    combine_kernel<<<1250, 256, 0, stream>>>(
        (const float4*)p0, (const float4*)(p0 + (size_t)NN * CC), (float4*)out);
}